// Round 6
// baseline (180.058 us; speedup 1.0000x reference)
//
#include <hip/hip_runtime.h>
#include <hip/hip_cooperative_groups.h>
#include <math.h>

namespace cg = cooperative_groups;

#define NVOX 16384
#define NRAYS 2048
#define STOPT 0.01f
#define FARP 100.0f

#define NCELLS 512          // 8x8x8 over [-1,1]^3
#define CELLW 0.25f
#define PAD 0.051f          // max voxel half-size (0.05) + slack
#define CAPV 96             // per-cell capacity (mean 32, ~11 sigma)
#define MAXC 192            // per-ray hit-cell list capacity
#define CAPH 256            // per-ray hit list capacity

#define GBLK 256
#define GGRID 1024          // 2 rays per block
#define GRPB 2

// ---------------- fused cooperative kernel: zero -> bin -> raster ----------------
__global__ __launch_bounds__(GBLK, 4) void fused_kernel(
    const float* __restrict__ pos, const float* __restrict__ siz,
    const float* __restrict__ den, const float* __restrict__ col,
    const float* __restrict__ rob, const float* __restrict__ rdb,
    float* __restrict__ out, int* __restrict__ cnt, float4* __restrict__ recs)
{
    cg::grid_group grid = cg::this_grid();
    const int tid  = threadIdx.x;
    const int gtid = blockIdx.x * GBLK + tid;

    // Phase 0: zero cell counters
    if (gtid < NCELLS) cnt[gtid] = 0;
    grid.sync();

    // Phase 1: bin voxels (cell of center; record {bmin,exp(den)},{bmax,id})
    if (gtid < NVOX) {
        const int v = gtid;
        const float px = pos[3*v], py = pos[3*v+1], pz = pos[3*v+2];
        const float h  = siz[v] * 0.5f;
        const int cx = min(7, max(0, (int)((px + 1.0f) * 4.0f)));
        const int cy = min(7, max(0, (int)((py + 1.0f) * 4.0f)));
        const int cz = min(7, max(0, (int)((pz + 1.0f) * 4.0f)));
        const int c  = cx + 8 * (cy + 8 * cz);
        const int slot = atomicAdd(&cnt[c], 1);
        if (slot < CAPV) {
            const int idx = (c * CAPV + slot) * 2;
            recs[idx]     = make_float4(px - h, py - h, pz - h, expf(den[v]));
            recs[idx + 1] = make_float4(px + h, py + h, pz + h, __int_as_float(v));
        }
    }
    grid.sync();

    // Phase 2: per-block raster of GRPB rays
    __shared__ int   s_cells[GRPB][MAXC];
    __shared__ float s_tn  [GRPB][CAPH];
    __shared__ float s_opv [GRPB][CAPH];
    __shared__ int   s_cid [GRPB][CAPH];
    __shared__ int   s_ncell[GRPB], s_nhit[GRPB];

    if (tid < GRPB) { s_ncell[tid] = 0; s_nhit[tid] = 0; }
    __syncthreads();

    const int ray0 = blockIdx.x * GRPB;
    float ivx[GRPB], ivy[GRPB], ivz[GRPB], ofx[GRPB], ofy[GRPB], ofz[GRPB];
#pragma unroll
    for (int r = 0; r < GRPB; ++r) {
        const int ray = ray0 + r;
        const float ox = rob[ray*3], oy = rob[ray*3+1], oz = rob[ray*3+2];
        const float dx = rdb[ray*3], dy = rdb[ray*3+1], dz = rdb[ray*3+2];
        ivx[r] = 1.0f/dx;      ivy[r] = 1.0f/dy;      ivz[r] = 1.0f/dz;
        ofx[r] = -ox*ivx[r];   ofy[r] = -oy*ivy[r];   ofz[r] = -oz*ivz[r];
    }

    // Phase A: conservative padded-cell cull for both rays
    for (int c = tid; c < NCELLS; c += GBLK) {
        const int cx = c & 7, cy = (c >> 3) & 7, cz = c >> 6;
        const float mnx = -1.0f + CELLW*cx - PAD, mxx = mnx + CELLW + 2.0f*PAD;
        const float mny = -1.0f + CELLW*cy - PAD, mxy = mny + CELLW + 2.0f*PAD;
        const float mnz = -1.0f + CELLW*cz - PAD, mxz = mnz + CELLW + 2.0f*PAD;
#pragma unroll
        for (int r = 0; r < GRPB; ++r) {
            const float t0x = fmaf(mnx, ivx[r], ofx[r]), t1x = fmaf(mxx, ivx[r], ofx[r]);
            const float t0y = fmaf(mny, ivy[r], ofy[r]), t1y = fmaf(mxy, ivy[r], ofy[r]);
            const float t0z = fmaf(mnz, ivz[r], ofz[r]), t1z = fmaf(mxz, ivz[r], ofz[r]);
            const float tn = fmaxf(fmaxf(fminf(t0x,t1x), fminf(t0y,t1y)), fminf(t0z,t1z));
            const float tf = fminf(fminf(fmaxf(t0x,t1x), fmaxf(t0y,t1y)), fmaxf(t0z,t1z));
            if (tf >= tn && tf > 0.0f) {
                const int k = atomicAdd(&s_ncell[r], 1);
                if (k < MAXC) s_cells[r][k] = c;
            }
        }
    }
    __syncthreads();

    // Phase B: 2 waves per ray; lanes test member voxels of hit cells
    const int wv = tid >> 6, lane = tid & 63;
    {
        const int r    = wv >> 1;        // ray index within block
        const int wsub = wv & 1;         // 0/1: which of the 2 waves on this ray
        const int nc = min(s_ncell[r], MAXC);
        for (int ci = wsub; ci < nc; ci += 2) {
            const int c = s_cells[r][ci];
            const int m = min(cnt[c], CAPV);
            for (int j = lane; j < m; j += 64) {
                const float4 A = recs[(c*CAPV + j)*2];
                const float4 B = recs[(c*CAPV + j)*2 + 1];
                const float t0x = fmaf(A.x, ivx[r], ofx[r]), t1x = fmaf(B.x, ivx[r], ofx[r]);
                const float t0y = fmaf(A.y, ivy[r], ofy[r]), t1y = fmaf(B.y, ivy[r], ofy[r]);
                const float t0z = fmaf(A.z, ivz[r], ofz[r]), t1z = fmaf(B.z, ivz[r], ofz[r]);
                const float tn = fmaxf(fmaxf(fminf(t0x,t1x), fminf(t0y,t1y)), fminf(t0z,t1z));
                const float tf = fminf(fminf(fmaxf(t0x,t1x), fmaxf(t0y,t1y)), fmaxf(t0z,t1z));
                if (tf > tn && tf > 0.0f) {
                    const float op = 1.0f - expf(-A.w * (tf - tn) * (1.0f/7.0f));
                    const int k = atomicAdd(&s_nhit[r], 1);
                    if (k < CAPH) {
                        s_tn [r][k] = tn;
                        s_opv[r][k] = op;
                        s_cid[r][k] = __float_as_int(B.w);
                    }
                }
            }
        }
    }
    __syncthreads();

    // Phase C: waves 0 and 2 composite rays 0 and 1 (O(n^2) exclusive product;
    // reference semantics: w_i = T_excl_i*op_i if T_excl_i >= STOP_T, order-free)
    if ((wv & 1) == 0) {
        const int r = wv >> 1;
        const int n = min(s_nhit[r], CAPH);
        float ar = 0.f, ag = 0.f, ab = 0.f, ad = 0.f, aw = 0.f;
        for (int i = lane; i < n; i += 64) {
            const float ti = s_tn[r][i], oi = s_opv[r][i];
            float T = 1.0f;
            for (int j = 0; j < n; ++j)
                T *= (s_tn[r][j] < ti) ? (1.0f - s_opv[r][j]) : 1.0f;
            const float w = (T >= STOPT) ? T * oi : 0.0f;
            const int c = s_cid[r][i];
            ar += w * col[c*3+0];
            ag += w * col[c*3+1];
            ab += w * col[c*3+2];
            ad += w * ti;
            aw += w;
        }
#pragma unroll
        for (int off = 32; off > 0; off >>= 1) {
            ar += __shfl_down(ar, off);
            ag += __shfl_down(ag, off);
            ab += __shfl_down(ab, off);
            ad += __shfl_down(ad, off);
            aw += __shfl_down(aw, off);
        }
        if (lane == 0) {
            const int ray = ray0 + r;
            out[ray*3+0] = ar;
            out[ray*3+1] = ag;
            out[ray*3+2] = ab;
            out[NRAYS*3 + ray] = (n > 0) ? ad : FARP;
            out[NRAYS*4 + ray] = aw;
        }
    }
}

// ---------------- 3-node fallback (round-5 structure) ----------------
__global__ __launch_bounds__(256) void bin_kernel(
    const float* __restrict__ pos, const float* __restrict__ siz,
    const float* __restrict__ den, int* __restrict__ cnt,
    float4* __restrict__ recs)
{
    const int v = blockIdx.x * 256 + threadIdx.x;
    if (v >= NVOX) return;
    const float px = pos[3*v], py = pos[3*v+1], pz = pos[3*v+2];
    const float h  = siz[v] * 0.5f;
    const int cx = min(7, max(0, (int)((px + 1.0f) * 4.0f)));
    const int cy = min(7, max(0, (int)((py + 1.0f) * 4.0f)));
    const int cz = min(7, max(0, (int)((pz + 1.0f) * 4.0f)));
    const int c  = cx + 8 * (cy + 8 * cz);
    const int slot = atomicAdd(&cnt[c], 1);
    if (slot < CAPV) {
        const int idx = (c * CAPV + slot) * 2;
        recs[idx]     = make_float4(px - h, py - h, pz - h, expf(den[v]));
        recs[idx + 1] = make_float4(px + h, py + h, pz + h, __int_as_float(v));
    }
}

__global__ __launch_bounds__(256) void raster_grid_kernel(
    const int* __restrict__ cnt, const float4* __restrict__ recs,
    const float* __restrict__ col,
    const float* __restrict__ rob, const float* __restrict__ rdb,
    float* __restrict__ out)
{
    __shared__ int   s_cells[MAXC];
    __shared__ float s_tn [CAPH];
    __shared__ float s_opv[CAPH];
    __shared__ int   s_cid[CAPH];
    __shared__ int   s_ncell, s_nhit;

    const int ray = blockIdx.x;
    const int tid = threadIdx.x;
    if (tid == 0) { s_ncell = 0; s_nhit = 0; }
    __syncthreads();

    const float ox = rob[ray*3], oy = rob[ray*3+1], oz = rob[ray*3+2];
    const float dx = rdb[ray*3], dy = rdb[ray*3+1], dz = rdb[ray*3+2];
    const float ivx = 1.0f/dx, ivy = 1.0f/dy, ivz = 1.0f/dz;
    const float ofx = -ox*ivx, ofy = -oy*ivy, ofz = -oz*ivz;

    for (int c = tid; c < NCELLS; c += 256) {
        const int cx = c & 7, cy = (c >> 3) & 7, cz = c >> 6;
        const float mnx = -1.0f + CELLW*cx - PAD, mxx = mnx + CELLW + 2.0f*PAD;
        const float mny = -1.0f + CELLW*cy - PAD, mxy = mny + CELLW + 2.0f*PAD;
        const float mnz = -1.0f + CELLW*cz - PAD, mxz = mnz + CELLW + 2.0f*PAD;
        const float t0x = fmaf(mnx, ivx, ofx), t1x = fmaf(mxx, ivx, ofx);
        const float t0y = fmaf(mny, ivy, ofy), t1y = fmaf(mxy, ivy, ofy);
        const float t0z = fmaf(mnz, ivz, ofz), t1z = fmaf(mxz, ivz, ofz);
        const float tn = fmaxf(fmaxf(fminf(t0x,t1x), fminf(t0y,t1y)), fminf(t0z,t1z));
        const float tf = fminf(fminf(fmaxf(t0x,t1x), fmaxf(t0y,t1y)), fmaxf(t0z,t1z));
        if (tf >= tn && tf > 0.0f) {
            const int k = atomicAdd(&s_ncell, 1);
            if (k < MAXC) s_cells[k] = c;
        }
    }
    __syncthreads();

    const int wv = tid >> 6, lane = tid & 63;
    const int nc = min(s_ncell, MAXC);
    for (int ci = wv; ci < nc; ci += 4) {
        const int c = s_cells[ci];
        const int m = min(cnt[c], CAPV);
        for (int j = lane; j < m; j += 64) {
            const float4 A = recs[(c*CAPV + j)*2];
            const float4 B = recs[(c*CAPV + j)*2 + 1];
            const float t0x = fmaf(A.x, ivx, ofx), t1x = fmaf(B.x, ivx, ofx);
            const float t0y = fmaf(A.y, ivy, ofy), t1y = fmaf(B.y, ivy, ofy);
            const float t0z = fmaf(A.z, ivz, ofz), t1z = fmaf(B.z, ivz, ofz);
            const float tn = fmaxf(fmaxf(fminf(t0x,t1x), fminf(t0y,t1y)), fminf(t0z,t1z));
            const float tf = fminf(fminf(fmaxf(t0x,t1x), fmaxf(t0y,t1y)), fmaxf(t0z,t1z));
            if (tf > tn && tf > 0.0f) {
                const float op = 1.0f - expf(-A.w * (tf - tn) * (1.0f/7.0f));
                const int k = atomicAdd(&s_nhit, 1);
                if (k < CAPH) {
                    s_tn[k]  = tn;
                    s_opv[k] = op;
                    s_cid[k] = __float_as_int(B.w);
                }
            }
        }
    }
    __syncthreads();

    if (wv == 0) {
        const int n = min(s_nhit, CAPH);
        float ar = 0.f, ag = 0.f, ab = 0.f, ad = 0.f, aw = 0.f;
        for (int i = lane; i < n; i += 64) {
            const float ti = s_tn[i], oi = s_opv[i];
            float T = 1.0f;
            for (int j = 0; j < n; ++j)
                T *= (s_tn[j] < ti) ? (1.0f - s_opv[j]) : 1.0f;
            const float w = (T >= STOPT) ? T * oi : 0.0f;
            const int c = s_cid[i];
            ar += w * col[c*3+0];
            ag += w * col[c*3+1];
            ab += w * col[c*3+2];
            ad += w * ti;
            aw += w;
        }
#pragma unroll
        for (int off = 32; off > 0; off >>= 1) {
            ar += __shfl_down(ar, off);
            ag += __shfl_down(ag, off);
            ab += __shfl_down(ab, off);
            ad += __shfl_down(ad, off);
            aw += __shfl_down(aw, off);
        }
        if (lane == 0) {
            out[ray*3+0] = ar;
            out[ray*3+1] = ag;
            out[ray*3+2] = ab;
            out[NRAYS*3 + ray] = (n > 0) ? ad : FARP;
            out[NRAYS*4 + ray] = aw;
        }
    }
}

extern "C" void kernel_launch(void* const* d_in, const int* in_sizes, int n_in,
                              void* d_out, int out_size, void* d_ws, size_t ws_size,
                              hipStream_t stream) {
    const float* pos = (const float*)d_in[0];
    const float* siz = (const float*)d_in[1];
    const float* den = (const float*)d_in[2];
    const float* col = (const float*)d_in[3];
    const float* rob = (const float*)d_in[4];
    const float* rdb = (const float*)d_in[5];
    float* out = (float*)d_out;

    int*    cnt  = (int*)d_ws;
    float4* recs = (float4*)((char*)d_ws + 4096);

    // Primary: single cooperative node (zero -> sync -> bin -> sync -> raster)
    void* args[] = { (void*)&pos, (void*)&siz, (void*)&den, (void*)&col,
                     (void*)&rob, (void*)&rdb, (void*)&out, (void*)&cnt, (void*)&recs };
    hipError_t err = hipLaunchCooperativeKernel((void*)fused_kernel,
                                                dim3(GGRID), dim3(GBLK),
                                                args, 0, stream);
    if (err != hipSuccess) {
        (void)hipGetLastError();  // clear error state; fall back to 3-node path
        hipMemsetAsync(cnt, 0, NCELLS * sizeof(int), stream);
        bin_kernel<<<NVOX/256, 256, 0, stream>>>(pos, siz, den, cnt, recs);
        raster_grid_kernel<<<NRAYS, 256, 0, stream>>>(cnt, recs, col, rob, rdb, out);
    }
}

// Round 7
// 66.770 us; speedup vs baseline: 2.6967x; 2.6967x over previous
//
#include <hip/hip_runtime.h>
#include <math.h>

#define NVOX 16384
#define NRAYS 2048
#define STOPT 0.01f
#define FARP 100.0f

#define NCELLS 512          // 8x8x8 over [-1,1]^3
#define CELLW 0.25f
#define PAD 0.051f          // max voxel half-size (0.05) + slack
#define CAPV 96             // per-cell capacity (mean 32, ~11 sigma)
#define MAXC 192            // per-ray hit-cell list capacity
#define CAPH 256            // per-ray hit list capacity

// ---------------- node 1: fused zero + bin (ONE block => intra-block sync) ----------------
__global__ __launch_bounds__(1024) void build_kernel(
    const float* __restrict__ pos, const float* __restrict__ siz,
    const float* __restrict__ den, int* __restrict__ cnt,
    float4* __restrict__ recs)
{
    const int tid = threadIdx.x;

    for (int i = tid; i < NCELLS; i += 1024) cnt[i] = 0;
    __syncthreads();

#pragma unroll 4
    for (int v = tid; v < NVOX; v += 1024) {
        const float px = pos[3*v], py = pos[3*v+1], pz = pos[3*v+2];
        const float h  = siz[v] * 0.5f;
        const int cx = min(7, max(0, (int)((px + 1.0f) * 4.0f)));
        const int cy = min(7, max(0, (int)((py + 1.0f) * 4.0f)));
        const int cz = min(7, max(0, (int)((pz + 1.0f) * 4.0f)));
        const int c  = cx + 8 * (cy + 8 * cz);
        const int slot = atomicAdd(&cnt[c], 1);
        if (slot < CAPV) {
            const int idx = (c * CAPV + slot) * 2;
            recs[idx]     = make_float4(px - h, py - h, pz - h, expf(den[v]));
            recs[idx + 1] = make_float4(px + h, py + h, pz + h, __int_as_float(v));
        }
    }
}

// ---------------- node 2: per-ray cull + test + composite ----------------
__global__ __launch_bounds__(256) void raster_grid_kernel(
    const int* __restrict__ cnt, const float4* __restrict__ recs,
    const float* __restrict__ col,
    const float* __restrict__ rob, const float* __restrict__ rdb,
    float* __restrict__ out)
{
    __shared__ int   s_cells[MAXC];
    __shared__ float s_tn [CAPH];
    __shared__ float s_opv[CAPH];
    __shared__ int   s_cid[CAPH];
    __shared__ int   s_ncell, s_nhit;

    const int ray = blockIdx.x;
    const int tid = threadIdx.x;
    if (tid == 0) { s_ncell = 0; s_nhit = 0; }
    __syncthreads();

    const float ox = rob[ray*3], oy = rob[ray*3+1], oz = rob[ray*3+2];
    const float dx = rdb[ray*3], dy = rdb[ray*3+1], dz = rdb[ray*3+2];
    const float ivx = 1.0f/dx, ivy = 1.0f/dy, ivz = 1.0f/dz;
    const float ofx = -ox*ivx, ofy = -oy*ivy, ofz = -oz*ivz;

    // Phase A: conservative padded-cell cull (512 cells / 256 threads = 2 iters)
    for (int c = tid; c < NCELLS; c += 256) {
        const int cx = c & 7, cy = (c >> 3) & 7, cz = c >> 6;
        const float mnx = -1.0f + CELLW*cx - PAD, mxx = mnx + CELLW + 2.0f*PAD;
        const float mny = -1.0f + CELLW*cy - PAD, mxy = mny + CELLW + 2.0f*PAD;
        const float mnz = -1.0f + CELLW*cz - PAD, mxz = mnz + CELLW + 2.0f*PAD;
        const float t0x = fmaf(mnx, ivx, ofx), t1x = fmaf(mxx, ivx, ofx);
        const float t0y = fmaf(mny, ivy, ofy), t1y = fmaf(mxy, ivy, ofy);
        const float t0z = fmaf(mnz, ivz, ofz), t1z = fmaf(mxz, ivz, ofz);
        const float tn = fmaxf(fmaxf(fminf(t0x,t1x), fminf(t0y,t1y)), fminf(t0z,t1z));
        const float tf = fminf(fminf(fmaxf(t0x,t1x), fmaxf(t0y,t1y)), fmaxf(t0z,t1z));
        if (tf >= tn && tf > 0.0f) {
            const int k = atomicAdd(&s_ncell, 1);
            if (k < MAXC) s_cells[k] = c;
        }
    }
    __syncthreads();

    // Phase B: 4 waves round-robin hit cells; lanes test member voxels
    const int wv = tid >> 6, lane = tid & 63;
    const int nc = min(s_ncell, MAXC);
    for (int ci = wv; ci < nc; ci += 4) {
        const int c = s_cells[ci];
        const int m = min(cnt[c], CAPV);
        for (int j = lane; j < m; j += 64) {
            const float4 A = recs[(c*CAPV + j)*2];
            const float4 B = recs[(c*CAPV + j)*2 + 1];
            const float t0x = fmaf(A.x, ivx, ofx), t1x = fmaf(B.x, ivx, ofx);
            const float t0y = fmaf(A.y, ivy, ofy), t1y = fmaf(B.y, ivy, ofy);
            const float t0z = fmaf(A.z, ivz, ofz), t1z = fmaf(B.z, ivz, ofz);
            const float tn = fmaxf(fmaxf(fminf(t0x,t1x), fminf(t0y,t1y)), fminf(t0z,t1z));
            const float tf = fminf(fminf(fmaxf(t0x,t1x), fmaxf(t0y,t1y)), fmaxf(t0z,t1z));
            if (tf > tn && tf > 0.0f) {
                const float op = 1.0f - expf(-A.w * (tf - tn) * (1.0f/7.0f));
                const int k = atomicAdd(&s_nhit, 1);
                if (k < CAPH) {
                    s_tn[k]  = tn;
                    s_opv[k] = op;
                    s_cid[k] = __float_as_int(B.w);
                }
            }
        }
    }
    __syncthreads();

    // Phase C: wave 0 composites via O(n^2) exclusive product
    // (reference semantics: w_i = T_excl_i*op_i if T_excl_i >= STOP_T, order-free)
    if (wv == 0) {
        const int n = min(s_nhit, CAPH);
        float ar = 0.f, ag = 0.f, ab = 0.f, ad = 0.f, aw = 0.f;
        for (int i = lane; i < n; i += 64) {
            const float ti = s_tn[i], oi = s_opv[i];
            float T = 1.0f;
            for (int j = 0; j < n; ++j)
                T *= (s_tn[j] < ti) ? (1.0f - s_opv[j]) : 1.0f;
            const float w = (T >= STOPT) ? T * oi : 0.0f;
            const int c = s_cid[i];
            ar += w * col[c*3+0];
            ag += w * col[c*3+1];
            ab += w * col[c*3+2];
            ad += w * ti;
            aw += w;
        }
#pragma unroll
        for (int off = 32; off > 0; off >>= 1) {
            ar += __shfl_down(ar, off);
            ag += __shfl_down(ag, off);
            ab += __shfl_down(ab, off);
            ad += __shfl_down(ad, off);
            aw += __shfl_down(aw, off);
        }
        if (lane == 0) {
            out[ray*3+0] = ar;
            out[ray*3+1] = ag;
            out[ray*3+2] = ab;
            out[NRAYS*3 + ray] = (n > 0) ? ad : FARP;
            out[NRAYS*4 + ray] = aw;
        }
    }
}

// ---------------- flat single-node fallback (round-4 kernel) ----------------
#define FB_CAP 256
#define FB_BLK 1024
#define FB_RPB 4

__global__ __launch_bounds__(FB_BLK) void raster_flat_kernel(
    const float* __restrict__ pos, const float* __restrict__ siz,
    const float* __restrict__ den, const float* __restrict__ col,
    const float* __restrict__ rob, const float* __restrict__ rdb,
    float* __restrict__ out)
{
    __shared__ float s_key[FB_RPB][FB_CAP];
    __shared__ float s_op [FB_RPB][FB_CAP];
    __shared__ int   s_cid[FB_RPB][FB_CAP];
    __shared__ int   s_cnt[FB_RPB];

    const int tid  = threadIdx.x;
    const int ray0 = blockIdx.x * FB_RPB;
    if (tid < FB_RPB) s_cnt[tid] = 0;
    __syncthreads();

    float ivx[FB_RPB], ivy[FB_RPB], ivz[FB_RPB], ofx[FB_RPB], ofy[FB_RPB], ofz[FB_RPB];
#pragma unroll
    for (int r = 0; r < FB_RPB; ++r) {
        const int ray = ray0 + r;
        const float ox = rob[ray*3], oy = rob[ray*3+1], oz = rob[ray*3+2];
        const float dx = rdb[ray*3], dy = rdb[ray*3+1], dz = rdb[ray*3+2];
        ivx[r] = 1.0f/dx; ivy[r] = 1.0f/dy; ivz[r] = 1.0f/dz;
        ofx[r] = -ox*ivx[r]; ofy[r] = -oy*ivy[r]; ofz[r] = -oz*ivz[r];
    }
#pragma unroll 4
    for (int v = tid; v < NVOX; v += FB_BLK) {
        const float px = pos[3*v], py = pos[3*v+1], pz = pos[3*v+2];
        const float h = siz[v]*0.5f;
        const float bnx = px-h, bxx = px+h, bny = py-h, bxy = py+h, bnz = pz-h, bxz = pz+h;
#pragma unroll
        for (int r = 0; r < FB_RPB; ++r) {
            const float t0x = fmaf(bnx, ivx[r], ofx[r]), t1x = fmaf(bxx, ivx[r], ofx[r]);
            const float t0y = fmaf(bny, ivy[r], ofy[r]), t1y = fmaf(bxy, ivy[r], ofy[r]);
            const float t0z = fmaf(bnz, ivz[r], ofz[r]), t1z = fmaf(bxz, ivz[r], ofz[r]);
            const float tn = fmaxf(fmaxf(fminf(t0x,t1x), fminf(t0y,t1y)), fminf(t0z,t1z));
            const float tf = fminf(fminf(fmaxf(t0x,t1x), fmaxf(t0y,t1y)), fmaxf(t0z,t1z));
            if (tf > tn && tf > 0.0f) {
                const float op = 1.0f - expf(-expf(den[v]) * (tf - tn) * (1.0f/7.0f));
                const int k = atomicAdd(&s_cnt[r], 1);
                if (k < FB_CAP) { s_key[r][k] = tn; s_op[r][k] = op; s_cid[r][k] = v; }
            }
        }
    }
    __syncthreads();

    const int wv = tid >> 6, lane = tid & 63;
    if (wv < FB_RPB) {
        const int n = min(s_cnt[wv], FB_CAP);
        float ar = 0.f, ag = 0.f, ab = 0.f, ad = 0.f, aw = 0.f;
        for (int i = lane; i < n; i += 64) {
            const float ti = s_key[wv][i], oi = s_op[wv][i];
            float T = 1.0f;
            for (int j = 0; j < n; ++j)
                T *= (s_key[wv][j] < ti) ? (1.0f - s_op[wv][j]) : 1.0f;
            const float w = (T >= STOPT) ? T * oi : 0.0f;
            const int c = s_cid[wv][i];
            ar += w*col[c*3+0]; ag += w*col[c*3+1]; ab += w*col[c*3+2];
            ad += w*ti; aw += w;
        }
#pragma unroll
        for (int off = 32; off > 0; off >>= 1) {
            ar += __shfl_down(ar, off); ag += __shfl_down(ag, off);
            ab += __shfl_down(ab, off); ad += __shfl_down(ad, off);
            aw += __shfl_down(aw, off);
        }
        if (lane == 0) {
            const int ray = ray0 + wv;
            out[ray*3+0] = ar; out[ray*3+1] = ag; out[ray*3+2] = ab;
            out[NRAYS*3 + ray] = (n > 0) ? ad : FARP;
            out[NRAYS*4 + ray] = aw;
        }
    }
}

extern "C" void kernel_launch(void* const* d_in, const int* in_sizes, int n_in,
                              void* d_out, int out_size, void* d_ws, size_t ws_size,
                              hipStream_t stream) {
    const float* pos = (const float*)d_in[0];
    const float* siz = (const float*)d_in[1];
    const float* den = (const float*)d_in[2];
    const float* col = (const float*)d_in[3];
    const float* rob = (const float*)d_in[4];
    const float* rdb = (const float*)d_in[5];
    float* out = (float*)d_out;

    const size_t need = 4096 + (size_t)NCELLS * CAPV * 2 * sizeof(float4);
    if (ws_size >= need) {
        int*    cnt  = (int*)d_ws;
        float4* recs = (float4*)((char*)d_ws + 4096);
        build_kernel<<<1, 1024, 0, stream>>>(pos, siz, den, cnt, recs);
        raster_grid_kernel<<<NRAYS, 256, 0, stream>>>(cnt, recs, col, rob, rdb, out);
    } else {
        raster_flat_kernel<<<NRAYS/FB_RPB, FB_BLK, 0, stream>>>(pos, siz, den, col, rob, rdb, out);
    }
}

// Round 8
// 34.434 us; speedup vs baseline: 5.2291x; 1.9391x over previous
//
#include <hip/hip_runtime.h>
#include <math.h>

#define NVOX 16384
#define NRAYS 2048
#define STOPT 0.01f
#define FARP 100.0f

#define NCELLS 512          // 8x8x8 over [-1,1]^3
#define CELLW 0.25f
#define PAD 0.051f          // max voxel half-size (0.05) + slack
#define CAPV 96             // per-cell capacity (mean 32, ~11 sigma)
#define MAXC 192            // per-ray hit-cell list capacity
#define CAPH 256            // per-ray hit list capacity

#define CPB 2               // cells per build block
#define BBLK 256

// ---------------- node 1: per-cell compaction build (no zero pass, no global atomics) ----
__global__ __launch_bounds__(BBLK) void cell_build_kernel(
    const float* __restrict__ pos, const float* __restrict__ siz,
    const float* __restrict__ den, int* __restrict__ cnt,
    float4* __restrict__ recs)
{
    __shared__ int s_c[CPB];
    const int tid = threadIdx.x;
    const int b   = blockIdx.x;          // owns cells [b*CPB, b*CPB+CPB)
    if (tid < CPB) s_c[tid] = 0;
    __syncthreads();

#pragma unroll 4
    for (int v = tid; v < NVOX; v += BBLK) {
        const float px = pos[3*v], py = pos[3*v+1], pz = pos[3*v+2];
        const int cx = min(7, max(0, (int)((px + 1.0f) * 4.0f)));
        const int cy = min(7, max(0, (int)((py + 1.0f) * 4.0f)));
        const int cz = min(7, max(0, (int)((pz + 1.0f) * 4.0f)));
        const int cell = cx + 8 * (cy + 8 * cz);
        if ((cell >> 1) == b) {                   // CPB == 2
            const float h = siz[v] * 0.5f;
            const int l = cell & (CPB - 1);
            const int slot = atomicAdd(&s_c[l], 1);   // LDS atomic; order irrelevant
            if (slot < CAPV) {
                const int idx = (cell * CAPV + slot) * 2;
                recs[idx]     = make_float4(px - h, py - h, pz - h, expf(den[v]));
                recs[idx + 1] = make_float4(px + h, py + h, pz + h, __int_as_float(v));
            }
        }
    }
    __syncthreads();
    if (tid < CPB) cnt[b * CPB + tid] = min(s_c[tid], CAPV);
}

// ---------------- node 2: per-ray cull + test + composite ----------------
__global__ __launch_bounds__(256) void raster_grid_kernel(
    const int* __restrict__ cnt, const float4* __restrict__ recs,
    const float* __restrict__ col,
    const float* __restrict__ rob, const float* __restrict__ rdb,
    float* __restrict__ out)
{
    __shared__ int   s_cells[MAXC];
    __shared__ float s_tn [CAPH];
    __shared__ float s_opv[CAPH];
    __shared__ int   s_cid[CAPH];
    __shared__ int   s_ncell, s_nhit;

    const int ray = blockIdx.x;
    const int tid = threadIdx.x;
    if (tid == 0) { s_ncell = 0; s_nhit = 0; }
    __syncthreads();

    const float ox = rob[ray*3], oy = rob[ray*3+1], oz = rob[ray*3+2];
    const float dx = rdb[ray*3], dy = rdb[ray*3+1], dz = rdb[ray*3+2];
    const float ivx = 1.0f/dx, ivy = 1.0f/dy, ivz = 1.0f/dz;
    const float ofx = -ox*ivx, ofy = -oy*ivy, ofz = -oz*ivz;

    // Phase A: conservative padded-cell cull (member-hit => padded-cell-hit)
    for (int c = tid; c < NCELLS; c += 256) {
        const int cx = c & 7, cy = (c >> 3) & 7, cz = c >> 6;
        const float mnx = -1.0f + CELLW*cx - PAD, mxx = mnx + CELLW + 2.0f*PAD;
        const float mny = -1.0f + CELLW*cy - PAD, mxy = mny + CELLW + 2.0f*PAD;
        const float mnz = -1.0f + CELLW*cz - PAD, mxz = mnz + CELLW + 2.0f*PAD;
        const float t0x = fmaf(mnx, ivx, ofx), t1x = fmaf(mxx, ivx, ofx);
        const float t0y = fmaf(mny, ivy, ofy), t1y = fmaf(mxy, ivy, ofy);
        const float t0z = fmaf(mnz, ivz, ofz), t1z = fmaf(mxz, ivz, ofz);
        const float tn = fmaxf(fmaxf(fminf(t0x,t1x), fminf(t0y,t1y)), fminf(t0z,t1z));
        const float tf = fminf(fminf(fmaxf(t0x,t1x), fmaxf(t0y,t1y)), fmaxf(t0z,t1z));
        if (tf >= tn && tf > 0.0f) {
            const int k = atomicAdd(&s_ncell, 1);
            if (k < MAXC) s_cells[k] = c;
        }
    }
    __syncthreads();

    // Phase B: 4 waves round-robin hit cells; lanes test member voxels
    const int wv = tid >> 6, lane = tid & 63;
    const int nc = min(s_ncell, MAXC);
    for (int ci = wv; ci < nc; ci += 4) {
        const int c = s_cells[ci];
        const int m = min(cnt[c], CAPV);
        for (int j = lane; j < m; j += 64) {
            const float4 A = recs[(c*CAPV + j)*2];
            const float4 B = recs[(c*CAPV + j)*2 + 1];
            const float t0x = fmaf(A.x, ivx, ofx), t1x = fmaf(B.x, ivx, ofx);
            const float t0y = fmaf(A.y, ivy, ofy), t1y = fmaf(B.y, ivy, ofy);
            const float t0z = fmaf(A.z, ivz, ofz), t1z = fmaf(B.z, ivz, ofz);
            const float tn = fmaxf(fmaxf(fminf(t0x,t1x), fminf(t0y,t1y)), fminf(t0z,t1z));
            const float tf = fminf(fminf(fmaxf(t0x,t1x), fmaxf(t0y,t1y)), fmaxf(t0z,t1z));
            if (tf > tn && tf > 0.0f) {
                const float op = 1.0f - expf(-A.w * (tf - tn) * (1.0f/7.0f));
                const int k = atomicAdd(&s_nhit, 1);
                if (k < CAPH) {
                    s_tn[k]  = tn;
                    s_opv[k] = op;
                    s_cid[k] = __float_as_int(B.w);
                }
            }
        }
    }
    __syncthreads();

    // Phase C: wave 0 composites via O(n^2) exclusive product
    // (reference semantics: w_i = T_excl_i*op_i if T_excl_i >= STOP_T, order-free)
    if (wv == 0) {
        const int n = min(s_nhit, CAPH);
        float ar = 0.f, ag = 0.f, ab = 0.f, ad = 0.f, aw = 0.f;
        for (int i = lane; i < n; i += 64) {
            const float ti = s_tn[i], oi = s_opv[i];
            float T = 1.0f;
            for (int j = 0; j < n; ++j)
                T *= (s_tn[j] < ti) ? (1.0f - s_opv[j]) : 1.0f;
            const float w = (T >= STOPT) ? T * oi : 0.0f;
            const int c = s_cid[i];
            ar += w * col[c*3+0];
            ag += w * col[c*3+1];
            ab += w * col[c*3+2];
            ad += w * ti;
            aw += w;
        }
#pragma unroll
        for (int off = 32; off > 0; off >>= 1) {
            ar += __shfl_down(ar, off);
            ag += __shfl_down(ag, off);
            ab += __shfl_down(ab, off);
            ad += __shfl_down(ad, off);
            aw += __shfl_down(aw, off);
        }
        if (lane == 0) {
            out[ray*3+0] = ar;
            out[ray*3+1] = ag;
            out[ray*3+2] = ab;
            out[NRAYS*3 + ray] = (n > 0) ? ad : FARP;
            out[NRAYS*4 + ray] = aw;
        }
    }
}

// ---------------- flat single-node fallback (round-4 kernel) ----------------
#define FB_CAP 256
#define FB_BLK 1024
#define FB_RPB 4

__global__ __launch_bounds__(FB_BLK) void raster_flat_kernel(
    const float* __restrict__ pos, const float* __restrict__ siz,
    const float* __restrict__ den, const float* __restrict__ col,
    const float* __restrict__ rob, const float* __restrict__ rdb,
    float* __restrict__ out)
{
    __shared__ float s_key[FB_RPB][FB_CAP];
    __shared__ float s_op [FB_RPB][FB_CAP];
    __shared__ int   s_cid[FB_RPB][FB_CAP];
    __shared__ int   s_cnt[FB_RPB];

    const int tid  = threadIdx.x;
    const int ray0 = blockIdx.x * FB_RPB;
    if (tid < FB_RPB) s_cnt[tid] = 0;
    __syncthreads();

    float ivx[FB_RPB], ivy[FB_RPB], ivz[FB_RPB], ofx[FB_RPB], ofy[FB_RPB], ofz[FB_RPB];
#pragma unroll
    for (int r = 0; r < FB_RPB; ++r) {
        const int ray = ray0 + r;
        const float ox = rob[ray*3], oy = rob[ray*3+1], oz = rob[ray*3+2];
        const float dx = rdb[ray*3], dy = rdb[ray*3+1], dz = rdb[ray*3+2];
        ivx[r] = 1.0f/dx; ivy[r] = 1.0f/dy; ivz[r] = 1.0f/dz;
        ofx[r] = -ox*ivx[r]; ofy[r] = -oy*ivy[r]; ofz[r] = -oz*ivz[r];
    }
#pragma unroll 4
    for (int v = tid; v < NVOX; v += FB_BLK) {
        const float px = pos[3*v], py = pos[3*v+1], pz = pos[3*v+2];
        const float h = siz[v]*0.5f;
        const float bnx = px-h, bxx = px+h, bny = py-h, bxy = py+h, bnz = pz-h, bxz = pz+h;
#pragma unroll
        for (int r = 0; r < FB_RPB; ++r) {
            const float t0x = fmaf(bnx, ivx[r], ofx[r]), t1x = fmaf(bxx, ivx[r], ofx[r]);
            const float t0y = fmaf(bny, ivy[r], ofy[r]), t1y = fmaf(bxy, ivy[r], ofy[r]);
            const float t0z = fmaf(bnz, ivz[r], ofz[r]), t1z = fmaf(bxz, ivz[r], ofz[r]);
            const float tn = fmaxf(fmaxf(fminf(t0x,t1x), fminf(t0y,t1y)), fminf(t0z,t1z));
            const float tf = fminf(fminf(fmaxf(t0x,t1x), fmaxf(t0y,t1y)), fmaxf(t0z,t1z));
            if (tf > tn && tf > 0.0f) {
                const float op = 1.0f - expf(-expf(den[v]) * (tf - tn) * (1.0f/7.0f));
                const int k = atomicAdd(&s_cnt[r], 1);
                if (k < FB_CAP) { s_key[r][k] = tn; s_op[r][k] = op; s_cid[r][k] = v; }
            }
        }
    }
    __syncthreads();

    const int wv = tid >> 6, lane = tid & 63;
    if (wv < FB_RPB) {
        const int n = min(s_cnt[wv], FB_CAP);
        float ar = 0.f, ag = 0.f, ab = 0.f, ad = 0.f, aw = 0.f;
        for (int i = lane; i < n; i += 64) {
            const float ti = s_key[wv][i], oi = s_op[wv][i];
            float T = 1.0f;
            for (int j = 0; j < n; ++j)
                T *= (s_key[wv][j] < ti) ? (1.0f - s_op[wv][j]) : 1.0f;
            const float w = (T >= STOPT) ? T * oi : 0.0f;
            const int c = s_cid[wv][i];
            ar += w*col[c*3+0]; ag += w*col[c*3+1]; ab += w*col[c*3+2];
            ad += w*ti; aw += w;
        }
#pragma unroll
        for (int off = 32; off > 0; off >>= 1) {
            ar += __shfl_down(ar, off); ag += __shfl_down(ag, off);
            ab += __shfl_down(ab, off); ad += __shfl_down(ad, off);
            aw += __shfl_down(aw, off);
        }
        if (lane == 0) {
            const int ray = ray0 + wv;
            out[ray*3+0] = ar; out[ray*3+1] = ag; out[ray*3+2] = ab;
            out[NRAYS*3 + ray] = (n > 0) ? ad : FARP;
            out[NRAYS*4 + ray] = aw;
        }
    }
}

extern "C" void kernel_launch(void* const* d_in, const int* in_sizes, int n_in,
                              void* d_out, int out_size, void* d_ws, size_t ws_size,
                              hipStream_t stream) {
    const float* pos = (const float*)d_in[0];
    const float* siz = (const float*)d_in[1];
    const float* den = (const float*)d_in[2];
    const float* col = (const float*)d_in[3];
    const float* rob = (const float*)d_in[4];
    const float* rdb = (const float*)d_in[5];
    float* out = (float*)d_out;

    const size_t need = 4096 + (size_t)NCELLS * CAPV * 2 * sizeof(float4);
    if (ws_size >= need) {
        int*    cnt  = (int*)d_ws;
        float4* recs = (float4*)((char*)d_ws + 4096);
        cell_build_kernel<<<NCELLS / CPB, BBLK, 0, stream>>>(pos, siz, den, cnt, recs);
        raster_grid_kernel<<<NRAYS, 256, 0, stream>>>(cnt, recs, col, rob, rdb, out);
    } else {
        raster_flat_kernel<<<NRAYS/FB_RPB, FB_BLK, 0, stream>>>(pos, siz, den, col, rob, rdb, out);
    }
}

// Round 9
// 27.695 us; speedup vs baseline: 6.5016x; 1.2434x over previous
//
#include <hip/hip_runtime.h>
#include <math.h>

#define NVOX 16384
#define NRAYS 2048
#define CAP 256             // per-ray hit capacity (expected ~15-40 hits)
#define BLK 1024
#define RPB 4               // rays per block; phase 2 uses one wave per ray
#define STOPT 0.01f
#define FARP 100.0f

// Single-node flat rasterizer, vectorized loads: 4 consecutive voxels per step
// = 3 float4 (positions) + 1 float4 (sizes) instead of 16 scalar dwords.
__global__ __launch_bounds__(BLK, 4) void raster_flat_kernel(
    const float* __restrict__ pos,   // (NVOX,3)
    const float* __restrict__ siz,   // (NVOX,)
    const float* __restrict__ den,   // (NVOX,)
    const float* __restrict__ col,   // (NVOX,3)
    const float* __restrict__ rob,   // (NRAYS,3)
    const float* __restrict__ rdb,   // (NRAYS,3)
    float* __restrict__ out)         // rgb[NRAYS*3] | depth[NRAYS] | weights[NRAYS]
{
    __shared__ float s_key[RPB][CAP];
    __shared__ float s_op [RPB][CAP];
    __shared__ int   s_cid[RPB][CAP];
    __shared__ int   s_cnt[RPB];

    const int tid  = threadIdx.x;
    const int ray0 = blockIdx.x * RPB;
    if (tid < RPB) s_cnt[tid] = 0;
    __syncthreads();

    // per-ray constants (block-uniform addresses -> scalar loads)
    float ivx[RPB], ivy[RPB], ivz[RPB], ofx[RPB], ofy[RPB], ofz[RPB];
#pragma unroll
    for (int r = 0; r < RPB; ++r) {
        const int ray = ray0 + r;
        const float ox = rob[ray*3], oy = rob[ray*3+1], oz = rob[ray*3+2];
        const float dx = rdb[ray*3], dy = rdb[ray*3+1], dz = rdb[ray*3+2];
        ivx[r] = 1.0f/dx;      ivy[r] = 1.0f/dy;      ivz[r] = 1.0f/dz;
        ofx[r] = -ox*ivx[r];   ofy[r] = -oy*ivy[r];   ofz[r] = -oz*ivz[r];
    }

    const float4* __restrict__ pos4 = (const float4*)pos;   // 12288 float4s
    const float4* __restrict__ siz4 = (const float4*)siz;   // 4096 float4s

    // Phase 1: slab-test every voxel against RPB rays; push hits to LDS.
    // Each thread handles 4 consecutive voxels per iteration (vectorized loads).
#pragma unroll
    for (int k = 0; k < NVOX / (BLK * 4); ++k) {
        const int g  = tid + k * BLK;        // float4-group index
        const float4 p0 = pos4[3*g + 0];
        const float4 p1 = pos4[3*g + 1];
        const float4 p2 = pos4[3*g + 2];
        const float4 s  = siz4[g];
        const int v0 = 4 * g;

        float vx[4], vy[4], vz[4], vh[4];
        vx[0] = p0.x; vy[0] = p0.y; vz[0] = p0.z; vh[0] = s.x;
        vx[1] = p0.w; vy[1] = p1.x; vz[1] = p1.y; vh[1] = s.y;
        vx[2] = p1.z; vy[2] = p1.w; vz[2] = p2.x; vh[2] = s.z;
        vx[3] = p2.y; vy[3] = p2.z; vz[3] = p2.w; vh[3] = s.w;

#pragma unroll
        for (int q = 0; q < 4; ++q) {
            const float h   = vh[q] * 0.5f;
            const float bnx = vx[q] - h, bxx = vx[q] + h;
            const float bny = vy[q] - h, bxy = vy[q] + h;
            const float bnz = vz[q] - h, bxz = vz[q] + h;
#pragma unroll
            for (int r = 0; r < RPB; ++r) {
                const float t0x = fmaf(bnx, ivx[r], ofx[r]), t1x = fmaf(bxx, ivx[r], ofx[r]);
                const float t0y = fmaf(bny, ivy[r], ofy[r]), t1y = fmaf(bxy, ivy[r], ofy[r]);
                const float t0z = fmaf(bnz, ivz[r], ofz[r]), t1z = fmaf(bxz, ivz[r], ofz[r]);
                const float tn = fmaxf(fmaxf(fminf(t0x,t1x), fminf(t0y,t1y)), fminf(t0z,t1z));
                const float tf = fminf(fminf(fmaxf(t0x,t1x), fmaxf(t0y,t1y)), fmaxf(t0z,t1z));
                if (tf > tn && tf > 0.0f) {
                    const int v = v0 + q;
                    const float op = 1.0f - expf(-expf(den[v]) * (tf - tn) * (1.0f/7.0f));
                    const int kk = atomicAdd(&s_cnt[r], 1);
                    if (kk < CAP) { s_key[r][kk] = tn; s_op[r][kk] = op; s_cid[r][kk] = v; }
                }
            }
        }
    }
    __syncthreads();

    // Phase 2: wave wv composites ray ray0+wv via O(n^2) exclusive product
    // (reference semantics: w_i = T_excl_i*op_i if T_excl_i >= STOP_T, order-free)
    const int wv = tid >> 6, lane = tid & 63;
    if (wv < RPB) {
        const int n = min(s_cnt[wv], CAP);
        float ar = 0.f, ag = 0.f, ab = 0.f, ad = 0.f, aw = 0.f;
        for (int i = lane; i < n; i += 64) {
            const float ti = s_key[wv][i], oi = s_op[wv][i];
            float T = 1.0f;
            for (int j = 0; j < n; ++j)
                T *= (s_key[wv][j] < ti) ? (1.0f - s_op[wv][j]) : 1.0f;   // LDS broadcast
            const float w = (T >= STOPT) ? T * oi : 0.0f;
            const int c = s_cid[wv][i];
            ar += w * col[c*3+0];
            ag += w * col[c*3+1];
            ab += w * col[c*3+2];
            ad += w * ti;
            aw += w;
        }
#pragma unroll
        for (int off = 32; off > 0; off >>= 1) {
            ar += __shfl_down(ar, off);
            ag += __shfl_down(ag, off);
            ab += __shfl_down(ab, off);
            ad += __shfl_down(ad, off);
            aw += __shfl_down(aw, off);
        }
        if (lane == 0) {
            const int ray = ray0 + wv;
            out[ray*3+0] = ar;
            out[ray*3+1] = ag;
            out[ray*3+2] = ab;
            out[NRAYS*3 + ray] = (n > 0) ? ad : FARP;
            out[NRAYS*4 + ray] = aw;
        }
    }
}

extern "C" void kernel_launch(void* const* d_in, const int* in_sizes, int n_in,
                              void* d_out, int out_size, void* d_ws, size_t ws_size,
                              hipStream_t stream) {
    const float* pos = (const float*)d_in[0];
    const float* siz = (const float*)d_in[1];
    const float* den = (const float*)d_in[2];
    const float* col = (const float*)d_in[3];
    const float* rob = (const float*)d_in[4];
    const float* rdb = (const float*)d_in[5];
    float* out = (float*)d_out;

    raster_flat_kernel<<<NRAYS / RPB, BLK, 0, stream>>>(pos, siz, den, col, rob, rdb, out);
}

// Round 10
// 27.577 us; speedup vs baseline: 6.5294x; 1.0043x over previous
//
#include <hip/hip_runtime.h>
#include <math.h>

#define NVOX 16384
#define NRAYS 2048
#define CAP 256             // per-ray hit capacity (expected ~15-40 hits)
#define BLK 1024
#define RPB 4               // rays per block; phase 2 uses one wave per ray
#define STOPT 0.01f
#define FARP 100.0f

// Single-node flat rasterizer, vectorized loads: 4 consecutive voxels per step
// = 3 float4 (positions) + 1 float4 (sizes) instead of 16 scalar dwords.
__global__ __launch_bounds__(BLK, 4) void raster_flat_kernel(
    const float* __restrict__ pos,   // (NVOX,3)
    const float* __restrict__ siz,   // (NVOX,)
    const float* __restrict__ den,   // (NVOX,)
    const float* __restrict__ col,   // (NVOX,3)
    const float* __restrict__ rob,   // (NRAYS,3)
    const float* __restrict__ rdb,   // (NRAYS,3)
    float* __restrict__ out)         // rgb[NRAYS*3] | depth[NRAYS] | weights[NRAYS]
{
    __shared__ float s_key[RPB][CAP];
    __shared__ float s_op [RPB][CAP];
    __shared__ int   s_cid[RPB][CAP];
    __shared__ int   s_cnt[RPB];

    const int tid  = threadIdx.x;
    const int ray0 = blockIdx.x * RPB;
    if (tid < RPB) s_cnt[tid] = 0;
    __syncthreads();

    // per-ray constants (block-uniform addresses -> scalar loads)
    float ivx[RPB], ivy[RPB], ivz[RPB], ofx[RPB], ofy[RPB], ofz[RPB];
#pragma unroll
    for (int r = 0; r < RPB; ++r) {
        const int ray = ray0 + r;
        const float ox = rob[ray*3], oy = rob[ray*3+1], oz = rob[ray*3+2];
        const float dx = rdb[ray*3], dy = rdb[ray*3+1], dz = rdb[ray*3+2];
        ivx[r] = 1.0f/dx;      ivy[r] = 1.0f/dy;      ivz[r] = 1.0f/dz;
        ofx[r] = -ox*ivx[r];   ofy[r] = -oy*ivy[r];   ofz[r] = -oz*ivz[r];
    }

    const float4* __restrict__ pos4 = (const float4*)pos;   // 12288 float4s
    const float4* __restrict__ siz4 = (const float4*)siz;   // 4096 float4s

    // Phase 1: slab-test every voxel against RPB rays; push hits to LDS.
    // Each thread handles 4 consecutive voxels per iteration (vectorized loads).
#pragma unroll
    for (int k = 0; k < NVOX / (BLK * 4); ++k) {
        const int g  = tid + k * BLK;        // float4-group index
        const float4 p0 = pos4[3*g + 0];
        const float4 p1 = pos4[3*g + 1];
        const float4 p2 = pos4[3*g + 2];
        const float4 s  = siz4[g];
        const int v0 = 4 * g;

        float vx[4], vy[4], vz[4], vh[4];
        vx[0] = p0.x; vy[0] = p0.y; vz[0] = p0.z; vh[0] = s.x;
        vx[1] = p0.w; vy[1] = p1.x; vz[1] = p1.y; vh[1] = s.y;
        vx[2] = p1.z; vy[2] = p1.w; vz[2] = p2.x; vh[2] = s.z;
        vx[3] = p2.y; vy[3] = p2.z; vz[3] = p2.w; vh[3] = s.w;

#pragma unroll
        for (int q = 0; q < 4; ++q) {
            const float h   = vh[q] * 0.5f;
            const float bnx = vx[q] - h, bxx = vx[q] + h;
            const float bny = vy[q] - h, bxy = vy[q] + h;
            const float bnz = vz[q] - h, bxz = vz[q] + h;
#pragma unroll
            for (int r = 0; r < RPB; ++r) {
                const float t0x = fmaf(bnx, ivx[r], ofx[r]), t1x = fmaf(bxx, ivx[r], ofx[r]);
                const float t0y = fmaf(bny, ivy[r], ofy[r]), t1y = fmaf(bxy, ivy[r], ofy[r]);
                const float t0z = fmaf(bnz, ivz[r], ofz[r]), t1z = fmaf(bxz, ivz[r], ofz[r]);
                const float tn = fmaxf(fmaxf(fminf(t0x,t1x), fminf(t0y,t1y)), fminf(t0z,t1z));
                const float tf = fminf(fminf(fmaxf(t0x,t1x), fmaxf(t0y,t1y)), fmaxf(t0z,t1z));
                if (tf > tn && tf > 0.0f) {
                    const int v = v0 + q;
                    const float op = 1.0f - expf(-expf(den[v]) * (tf - tn) * (1.0f/7.0f));
                    const int kk = atomicAdd(&s_cnt[r], 1);
                    if (kk < CAP) { s_key[r][kk] = tn; s_op[r][kk] = op; s_cid[r][kk] = v; }
                }
            }
        }
    }
    __syncthreads();

    // Phase 2: wave wv composites ray ray0+wv via O(n^2) exclusive product
    // (reference semantics: w_i = T_excl_i*op_i if T_excl_i >= STOP_T, order-free)
    const int wv = tid >> 6, lane = tid & 63;
    if (wv < RPB) {
        const int n = min(s_cnt[wv], CAP);
        float ar = 0.f, ag = 0.f, ab = 0.f, ad = 0.f, aw = 0.f;
        for (int i = lane; i < n; i += 64) {
            const float ti = s_key[wv][i], oi = s_op[wv][i];
            float T = 1.0f;
            for (int j = 0; j < n; ++j)
                T *= (s_key[wv][j] < ti) ? (1.0f - s_op[wv][j]) : 1.0f;   // LDS broadcast
            const float w = (T >= STOPT) ? T * oi : 0.0f;
            const int c = s_cid[wv][i];
            ar += w * col[c*3+0];
            ag += w * col[c*3+1];
            ab += w * col[c*3+2];
            ad += w * ti;
            aw += w;
        }
#pragma unroll
        for (int off = 32; off > 0; off >>= 1) {
            ar += __shfl_down(ar, off);
            ag += __shfl_down(ag, off);
            ab += __shfl_down(ab, off);
            ad += __shfl_down(ad, off);
            aw += __shfl_down(aw, off);
        }
        if (lane == 0) {
            const int ray = ray0 + wv;
            out[ray*3+0] = ar;
            out[ray*3+1] = ag;
            out[ray*3+2] = ab;
            out[NRAYS*3 + ray] = (n > 0) ? ad : FARP;
            out[NRAYS*4 + ray] = aw;
        }
    }
}

extern "C" void kernel_launch(void* const* d_in, const int* in_sizes, int n_in,
                              void* d_out, int out_size, void* d_ws, size_t ws_size,
                              hipStream_t stream) {
    const float* pos = (const float*)d_in[0];
    const float* siz = (const float*)d_in[1];
    const float* den = (const float*)d_in[2];
    const float* col = (const float*)d_in[3];
    const float* rob = (const float*)d_in[4];
    const float* rdb = (const float*)d_in[5];
    float* out = (float*)d_out;

    raster_flat_kernel<<<NRAYS / RPB, BLK, 0, stream>>>(pos, siz, den, col, rob, rdb, out);
}

// Round 11
// 23.862 us; speedup vs baseline: 7.5459x; 1.1557x over previous
//
#include <hip/hip_runtime.h>
#include <math.h>

#define NVOX 16384
#define NRAYS 2048
#define CAP 256             // per-ray hit capacity (expected ~15-40 hits)
#define BLK 1024
#define RPB 4               // rays per block; phase 2 uses one wave per ray
#define STOPT 0.01f
#define FARP 100.0f

// Single-node flat rasterizer.
// Centered slab test: tc = fma(p,iv,of); tn_ax = fma(-h,|iv|,tc); tf_ax = fma(h,|iv|,tc)
// => 9 fma + max3 + min3 + 2 cmp per test (no per-axis min/max, no bmin/bmax prep).
__global__ __launch_bounds__(BLK, 4) void raster_flat_kernel(
    const float* __restrict__ pos,   // (NVOX,3)
    const float* __restrict__ siz,   // (NVOX,)
    const float* __restrict__ den,   // (NVOX,)
    const float* __restrict__ col,   // (NVOX,3)
    const float* __restrict__ rob,   // (NRAYS,3)
    const float* __restrict__ rdb,   // (NRAYS,3)
    float* __restrict__ out)         // rgb[NRAYS*3] | depth[NRAYS] | weights[NRAYS]
{
    __shared__ float s_key[RPB][CAP];
    __shared__ float s_op [RPB][CAP];
    __shared__ int   s_cid[RPB][CAP];
    __shared__ int   s_cnt[RPB];

    const int tid  = threadIdx.x;
    const int ray0 = blockIdx.x * RPB;
    if (tid < RPB) s_cnt[tid] = 0;
    __syncthreads();

    // per-ray constants (block-uniform addresses -> scalar loads)
    float ivx[RPB], ivy[RPB], ivz[RPB];      // 1/d
    float aix[RPB], aiy[RPB], aiz[RPB];      // |1/d|
    float ofx[RPB], ofy[RPB], ofz[RPB];      // -o/d
#pragma unroll
    for (int r = 0; r < RPB; ++r) {
        const int ray = ray0 + r;
        const float ox = rob[ray*3], oy = rob[ray*3+1], oz = rob[ray*3+2];
        const float dx = rdb[ray*3], dy = rdb[ray*3+1], dz = rdb[ray*3+2];
        ivx[r] = 1.0f/dx;      ivy[r] = 1.0f/dy;      ivz[r] = 1.0f/dz;
        aix[r] = fabsf(ivx[r]); aiy[r] = fabsf(ivy[r]); aiz[r] = fabsf(ivz[r]);
        ofx[r] = -ox*ivx[r];   ofy[r] = -oy*ivy[r];   ofz[r] = -oz*ivz[r];
    }

    const float4* __restrict__ pos4 = (const float4*)pos;   // 12288 float4s
    const float4* __restrict__ siz4 = (const float4*)siz;   // 4096 float4s

    // Phase 1: slab-test every voxel against RPB rays; push hits to LDS.
    // Each thread handles 4 consecutive voxels per iteration (vectorized loads).
#pragma unroll
    for (int k = 0; k < NVOX / (BLK * 4); ++k) {
        const int g  = tid + k * BLK;        // float4-group index
        const float4 p0 = pos4[3*g + 0];
        const float4 p1 = pos4[3*g + 1];
        const float4 p2 = pos4[3*g + 2];
        const float4 s  = siz4[g];
        const int v0 = 4 * g;

        float vx[4], vy[4], vz[4], vh[4];
        vx[0] = p0.x; vy[0] = p0.y; vz[0] = p0.z; vh[0] = s.x;
        vx[1] = p0.w; vy[1] = p1.x; vz[1] = p1.y; vh[1] = s.y;
        vx[2] = p1.z; vy[2] = p1.w; vz[2] = p2.x; vh[2] = s.z;
        vx[3] = p2.y; vy[3] = p2.z; vz[3] = p2.w; vh[3] = s.w;

#pragma unroll
        for (int q = 0; q < 4; ++q) {
            const float h = vh[q] * 0.5f;
            const float px = vx[q], py = vy[q], pz = vz[q];
#pragma unroll
            for (int r = 0; r < RPB; ++r) {
                const float tcx = fmaf(px, ivx[r], ofx[r]);
                const float tcy = fmaf(py, ivy[r], ofy[r]);
                const float tcz = fmaf(pz, ivz[r], ofz[r]);
                const float tnx = fmaf(-h, aix[r], tcx);
                const float tny = fmaf(-h, aiy[r], tcy);
                const float tnz = fmaf(-h, aiz[r], tcz);
                const float tfx = fmaf( h, aix[r], tcx);
                const float tfy = fmaf( h, aiy[r], tcy);
                const float tfz = fmaf( h, aiz[r], tcz);
                const float tn = fmaxf(fmaxf(tnx, tny), tnz);   // v_max3
                const float tf = fminf(fminf(tfx, tfy), tfz);   // v_min3
                if (tf > tn && tf > 0.0f) {
                    const int v = v0 + q;
                    const float op = 1.0f - expf(-expf(den[v]) * (tf - tn) * (1.0f/7.0f));
                    const int kk = atomicAdd(&s_cnt[r], 1);
                    if (kk < CAP) { s_key[r][kk] = tn; s_op[r][kk] = op; s_cid[r][kk] = v; }
                }
            }
        }
    }
    __syncthreads();

    // Phase 2: wave wv composites ray ray0+wv via O(n^2) exclusive product
    // (reference semantics: w_i = T_excl_i*op_i if T_excl_i >= STOP_T, order-free)
    const int wv = tid >> 6, lane = tid & 63;
    if (wv < RPB) {
        const int n = min(s_cnt[wv], CAP);
        float ar = 0.f, ag = 0.f, ab = 0.f, ad = 0.f, aw = 0.f;
        for (int i = lane; i < n; i += 64) {
            const float ti = s_key[wv][i], oi = s_op[wv][i];
            float T = 1.0f;
            for (int j = 0; j < n; ++j)
                T *= (s_key[wv][j] < ti) ? (1.0f - s_op[wv][j]) : 1.0f;   // LDS broadcast
            const float w = (T >= STOPT) ? T * oi : 0.0f;
            const int c = s_cid[wv][i];
            ar += w * col[c*3+0];
            ag += w * col[c*3+1];
            ab += w * col[c*3+2];
            ad += w * ti;
            aw += w;
        }
#pragma unroll
        for (int off = 32; off > 0; off >>= 1) {
            ar += __shfl_down(ar, off);
            ag += __shfl_down(ag, off);
            ab += __shfl_down(ab, off);
            ad += __shfl_down(ad, off);
            aw += __shfl_down(aw, off);
        }
        if (lane == 0) {
            const int ray = ray0 + wv;
            out[ray*3+0] = ar;
            out[ray*3+1] = ag;
            out[ray*3+2] = ab;
            out[NRAYS*3 + ray] = (n > 0) ? ad : FARP;
            out[NRAYS*4 + ray] = aw;
        }
    }
}

extern "C" void kernel_launch(void* const* d_in, const int* in_sizes, int n_in,
                              void* d_out, int out_size, void* d_ws, size_t ws_size,
                              hipStream_t stream) {
    const float* pos = (const float*)d_in[0];
    const float* siz = (const float*)d_in[1];
    const float* den = (const float*)d_in[2];
    const float* col = (const float*)d_in[3];
    const float* rob = (const float*)d_in[4];
    const float* rdb = (const float*)d_in[5];
    float* out = (float*)d_out;

    raster_flat_kernel<<<NRAYS / RPB, BLK, 0, stream>>>(pos, siz, den, col, rob, rdb, out);
}